// Round 10
// baseline (988.225 us; speedup 1.0000x reference)
//
#include <hip/hip_runtime.h>
#include <math.h>

// Problem constants (fixed by setup_inputs): B=4, N=2048, C=128, H=6, K=8
#define NFIX 2048
#define HH 6
#define KNN 8
#define NSLOPE 0.2f
#define EPSF 1e-6f
#define LNEPSF 1e-5f
// 0.125 (softmax scale) * log2(e), folded into Wq rows so S-MFMA output is exp2-ready
#define QSCALE 0.18033688011112042f

typedef unsigned short ushort_t;
typedef unsigned int uint_t;
typedef __attribute__((ext_vector_type(8))) short bf16x8;
typedef __attribute__((ext_vector_type(4))) short bf16x4;
typedef __attribute__((ext_vector_type(8))) _Float16 f16x8;
typedef __attribute__((ext_vector_type(4))) _Float16 f16x4;
typedef __attribute__((ext_vector_type(16))) float f32x16;
typedef __attribute__((ext_vector_type(4))) float f32x4;

__device__ __forceinline__ ushort_t f2bf(float f) {
  union { float f; unsigned u; } v; v.f = f;
  unsigned r = v.u + 0x7fff + ((v.u >> 16) & 1);   // RNE
  return (ushort_t)(r >> 16);
}
__device__ __forceinline__ float bf2f(ushort_t u) {
  union { uint_t u; float f; } v; v.u = ((uint_t)u) << 16; return v.f;
}
__device__ __forceinline__ uint_t pack2(float a, float b) {
  return (uint_t)f2bf(a) | ((uint_t)f2bf(b) << 16);
}

#define LOAD12(dst, ptr) { \
  float4 _r0 = *(const float4*)((ptr));   \
  float4 _r1 = *(const float4*)((ptr)+4); \
  float4 _r2 = *(const float4*)((ptr)+8); \
  dst[0]=_r0.x; dst[1]=_r0.y; dst[2]=_r0.z; dst[3]=_r0.w; \
  dst[4]=_r1.x; dst[5]=_r1.y; dst[6]=_r1.z; dst[7]=_r1.w; \
  dst[8]=_r2.x; dst[9]=_r2.y; dst[10]=_r2.z; dst[11]=_r2.w; }

__device__ __forceinline__ void vnleaky3(const float* p, const float* dv, float* out) {
  float dot = p[0]*dv[0] + p[1]*dv[1] + p[2]*dv[2];
  float dsq = dv[0]*dv[0] + dv[1]*dv[1] + dv[2]*dv[2] + EPSF;
  float f = dot / dsq;
#pragma unroll
  for (int d = 0; d < 3; ++d) {
    float neg = p[d] - f * dv[d];
    out[d] = NSLOPE * p[d] + (1.f - NSLOPE) * ((dot >= 0.f) ? p[d] : neg);
  }
}

// ---------------- weight prep ----------------
// Wall bf16 [1664][128] (qkv+conv1 GEMM A). Af16 fp16 [128][512] = [M2 | W2b] rows c.
// fp32: W3t | U3t | W4t | U4t. Threads: 212992+49152+16384+131072 = 409600 = 1600*256.
__global__ void prep_weights(const float* __restrict__ Wq, const float* __restrict__ Wk,
                             const float* __restrict__ Wv, const float* __restrict__ Wo,
                             const float* __restrict__ W1, const float* __restrict__ U1,
                             const float* __restrict__ W2, const float* __restrict__ W3,
                             const float* __restrict__ U3, const float* __restrict__ W4,
                             const float* __restrict__ U4,
                             ushort_t* __restrict__ Wall, _Float16* __restrict__ Af16,
                             float* __restrict__ W3t, float* __restrict__ U3t,
                             float* __restrict__ W4t, float* __restrict__ U4t) {
  int idx = blockIdx.x * 256 + threadIdx.x;
  if (idx < 212992) {
    int m = idx >> 7, c = idx & 127;
    float val;
    if (m < 384)       val = Wq[m*128 + c] * QSCALE;
    else if (m < 768)  val = Wk[(m-384)*128 + c];
    else if (m < 1152) val = Wv[(m-768)*128 + c];
    else {
      int j = m - 1152;
      if (j < 128)      val = W1[j*256 + c];
      else if (j < 256) val = U1[(j-128)*256 + c];
      else if (j < 384) { int o = j-256; val = W1[o*256 + 128 + c] - W1[o*256 + c]; }
      else              { int o = j-384; val = U1[o*256 + 128 + c] - U1[o*256 + c]; }
    }
    Wall[idx] = f2bf(val); return;
  }
  idx -= 212992;
  if (idx < 49152) {
    int j = idx / 128, c = idx % 128;   // M2[c][j] = (W2a@Wo)[c][j]
    float s = 0.f;
    for (int cp = 0; cp < 128; ++cp) s += W2[c*256 + cp] * Wo[cp*384 + j];
    Af16[(size_t)c*512 + j] = (_Float16)s; return;
  }
  idx -= 49152;
  if (idx < 16384) {
    int c2 = idx / 128, c = idx % 128;
    Af16[(size_t)c*512 + 384 + c2] = (_Float16)W2[c*256 + 128 + c2]; return;
  }
  idx -= 16384;
  if (idx < 32768) { int c = idx / 256, o = idx % 256; W3t[idx] = W3[o*128 + c]; return; }
  idx -= 32768;
  if (idx < 32768) { int c = idx / 256, o = idx % 256; U3t[idx] = U3[o*128 + c]; return; }
  idx -= 32768;
  if (idx < 32768) { int c = idx / 128, o = idx % 128; W4t[idx] = W4[o*256 + c]; return; }
  idx -= 32768;
  if (idx < 32768) { int c = idx / 128, o = idx % 128; U4t[idx] = U4[o*256 + c]; return; }
}

// ---------------- LN1: raw x -> xbp (bf16 de-interleaved, normalized) + xdi (fp32 raw de-interleaved) ----------------
__global__ __launch_bounds__(128) void ln1_kernel(const float* __restrict__ in,
                                                  ushort_t* __restrict__ xbp,
                                                  float* __restrict__ xdi,
                                                  const float* __restrict__ g,
                                                  const float* __restrict__ b) {
  int bn = blockIdx.x;
  int c = threadIdx.x;
  const float* row = in + (size_t)bn * 384;
  float x0 = row[c*3+0], x1 = row[c*3+1], x2 = row[c*3+2];
  float nv = sqrtf(x0*x0 + x1*x1 + x2*x2 + EPSF);
  float s1 = nv, s2 = nv*nv;
#pragma unroll
  for (int off = 32; off >= 1; off >>= 1) {
    s1 += __shfl_down(s1, off);
    s2 += __shfl_down(s2, off);
  }
  __shared__ float red[4];
  int lane = threadIdx.x & 63, w = threadIdx.x >> 6;
  if (lane == 0) { red[w*2] = s1; red[w*2+1] = s2; }
  __syncthreads();
  float tot1 = red[0] + red[2], tot2 = red[1] + red[3];
  float mu  = tot1 * (1.f/128.f);
  float var = tot2 * (1.f/128.f) - mu*mu;
  float rsig = rsqrtf(var + LNEPSF);
  float nnew = g[c] * ((nv - mu) * rsig) + b[c];
  float sc = nnew / nv;
  size_t rb = (size_t)bn * 384;
  xbp[rb + c]       = f2bf(x0*sc);
  xbp[rb + 128 + c] = f2bf(x1*sc);
  xbp[rb + 256 + c] = f2bf(x2*sc);
  xdi[rb + c]       = x0;
  xdi[rb + 128 + c] = x1;
  xdi[rb + 256 + c] = x2;
}

// ---------------- LN2: de-interleaved fp32 in/out ----------------
__global__ __launch_bounds__(128) void ln2_kernel(const float* __restrict__ in,
                                                  float* __restrict__ out,
                                                  const float* __restrict__ g,
                                                  const float* __restrict__ b) {
  int bn = blockIdx.x;
  int c = threadIdx.x;
  size_t base = (size_t)bn * 384;
  float x0 = in[base + c], x1 = in[base + 128 + c], x2 = in[base + 256 + c];
  float nv = sqrtf(x0*x0 + x1*x1 + x2*x2 + EPSF);
  float s1 = nv, s2 = nv*nv;
#pragma unroll
  for (int off = 32; off >= 1; off >>= 1) {
    s1 += __shfl_down(s1, off);
    s2 += __shfl_down(s2, off);
  }
  __shared__ float red[4];
  int lane = threadIdx.x & 63, w = threadIdx.x >> 6;
  if (lane == 0) { red[w*2] = s1; red[w*2+1] = s2; }
  __syncthreads();
  float tot1 = red[0] + red[2], tot2 = red[1] + red[3];
  float mu  = tot1 * (1.f/128.f);
  float var = tot2 * (1.f/128.f) - mu*mu;
  float rsig = rsqrtf(var + LNEPSF);
  float nnew = g[c] * ((nv - mu) * rsig) + b[c];
  float sc = nnew / nv;
  out[base + c]       = x0*sc;
  out[base + 128 + c] = x1*sc;
  out[base + 256 + c] = x2*sc;
}

// ---------------- fused QKV + conv1 MFMA GEMM (unchanged) ----------------
#define XT_PITCH 132
#define WT_PITCH 132
#define TR_PITCH 36
__global__ __launch_bounds__(256, 2) void qkv_conv1_mfma(
    const ushort_t* __restrict__ xb, const ushort_t* __restrict__ Wall,
    ushort_t* __restrict__ q, ushort_t* __restrict__ k, ushort_t* __restrict__ v,
    float* __restrict__ YZf, float* __restrict__ NBf) {
  __shared__ ushort_t xs[128*XT_PITCH];
  __shared__ ushort_t wt[32*WT_PITCH];
  __shared__ float tr[4][32*TR_PITCH];
  int nb = blockIdx.x % 192;
  int mq = blockIdx.x / 192;
  int n0 = nb * 128;
  int t = threadIdx.x;
  int w = t >> 6, lane = t & 63, ql = lane & 31, hl = lane >> 5;
  for (int idx = t; idx < 2048; idx += 256) {
    int n = idx >> 4, c16 = idx & 15;
    bf16x8 gv = *(const bf16x8*)&xb[(size_t)(n0 + n)*128 + c16*8];
    ushort_t* dst = &xs[n*XT_PITCH + c16*8];
    *(bf16x4*)dst = __builtin_shufflevector(gv, gv, 0, 1, 2, 3);
    *(bf16x4*)(dst+4) = __builtin_shufflevector(gv, gv, 4, 5, 6, 7);
  }
  __syncthreads();
  bf16x8 xf[8];
  {
    const ushort_t* xr = &xs[(w*32 + ql)*XT_PITCH + hl*8];
#pragma unroll
    for (int cs = 0; cs < 8; ++cs) {
      bf16x4 lo = *(const bf16x4*)(xr + cs*16);
      bf16x4 hi = *(const bf16x4*)(xr + cs*16 + 4);
      xf[cs] = __builtin_shufflevector(lo, hi, 0, 1, 2, 3, 4, 5, 6, 7);
    }
  }
  int ng = n0 + w*32 + ql;
  int pt = ng / 3;
  int d  = ng - 3*pt;
  float* trw = tr[w];
  for (int mt = 0; mt < 13; ++mt) {
    int m0 = mq*416 + mt*32;
    __syncthreads();
    for (int idx = t; idx < 512; idx += 256) {
      int mm = idx >> 4, c16 = idx & 15;
      bf16x8 gv = *(const bf16x8*)&Wall[(size_t)(m0 + mm)*128 + c16*8];
      ushort_t* dst = &wt[mm*WT_PITCH + c16*8];
      *(bf16x4*)dst = __builtin_shufflevector(gv, gv, 0, 1, 2, 3);
      *(bf16x4*)(dst+4) = __builtin_shufflevector(gv, gv, 4, 5, 6, 7);
    }
    __syncthreads();
    f32x16 acc;
#pragma unroll
    for (int r = 0; r < 16; ++r) acc[r] = 0.f;
    const ushort_t* wr = &wt[ql*WT_PITCH + hl*8];
#pragma unroll
    for (int cs = 0; cs < 8; ++cs) {
      bf16x4 lo = *(const bf16x4*)(wr + cs*16);
      bf16x4 hi = *(const bf16x4*)(wr + cs*16 + 4);
      bf16x8 af = __builtin_shufflevector(lo, hi, 0, 1, 2, 3, 4, 5, 6, 7);
      acc = __builtin_amdgcn_mfma_f32_32x32x16_bf16(af, xf[cs], acc, 0, 0, 0);
    }
#pragma unroll
    for (int r = 0; r < 16; ++r) {
      int mrow = (r&3) + 8*(r>>2) + 4*hl;
      trw[ql*TR_PITCH + mrow] = acc[r];
    }
    asm volatile("s_waitcnt lgkmcnt(0)" ::: "memory");
    float4 c0 = *(float4*)&trw[ql*TR_PITCH + hl*16 + 0];
    float4 c1 = *(float4*)&trw[ql*TR_PITCH + hl*16 + 4];
    float4 c2 = *(float4*)&trw[ql*TR_PITCH + hl*16 + 8];
    float4 c3 = *(float4*)&trw[ql*TR_PITCH + hl*16 + 12];
    asm volatile("s_waitcnt lgkmcnt(0)" ::: "memory");
    int mg = m0 + hl*16;
    if (m0 < 1152) {
      uint4 s0, s1;
      s0.x = pack2(c0.x, c0.y); s0.y = pack2(c0.z, c0.w);
      s0.z = pack2(c1.x, c1.y); s0.w = pack2(c1.z, c1.w);
      s1.x = pack2(c2.x, c2.y); s1.y = pack2(c2.z, c2.w);
      s1.z = pack2(c3.x, c3.y); s1.w = pack2(c3.z, c3.w);
      ushort_t* dst;
      if (m0 < 384)       dst = q + (size_t)pt*1152 + d*384 + mg;
      else if (m0 < 768)  dst = k + (size_t)pt*1152 + d*384 + (mg - 384);
      else                dst = v + (size_t)pt*1152 + d*384 + (mg - 768);
      *(uint4*)dst = s0;
      *(uint4*)(dst + 8) = s1;
    } else {
      int mat = mg - 1152;
      int sub = mat >> 7, o = mat & 127;
      float* base = (sub < 2) ? YZf : NBf;
      float* dst = base + (size_t)pt*768 + d*256 + (sub & 1)*128 + o;
      *(float4*)dst = c0;
      *(float4*)(dst + 4) = c1;
      *(float4*)(dst + 8) = c2;
      *(float4*)(dst + 12) = c3;
    }
  }
}

// ---------------- conv1 post: gather + vnleaky + mean -> kmf16 [n=(pt*3+d)][o] fp16 ----------------
__global__ __launch_bounds__(128) void conv1_post(const float* __restrict__ YZf,
    const float* __restrict__ NBf, const int* __restrict__ knn_index,
    _Float16* __restrict__ kmf16) {
  int bn = blockIdx.x;
  int b = bn / NFIX, n = bn % NFIX;
  int t = threadIdx.x;
  __shared__ int sidx[KNN];
  if (t < KNN) sidx[t] = knn_index[(b*KNN + t)*NFIX + n];
  __syncthreads();
  float yb[3], zb[3];
#pragma unroll
  for (int d = 0; d < 3; ++d) {
    yb[d] = NBf[(size_t)bn*768 + d*256 + t];
    zb[d] = NBf[(size_t)bn*768 + d*256 + 128 + t];
  }
  float om[3] = {0.f, 0.f, 0.f};
#pragma unroll
  for (int kk = 0; kk < KNN; ++kk) {
    const float* r = YZf + (size_t)sidx[kk]*768;
    float p[3], dd[3];
#pragma unroll
    for (int d = 0; d < 3; ++d) {
      p[d]  = r[d*256 + t] + yb[d];
      dd[d] = r[d*256 + 128 + t] + zb[d];
    }
    float res[3];
    vnleaky3(p, dd, res);
    om[0] += res[0]; om[1] += res[1]; om[2] += res[2];
  }
#pragma unroll
  for (int d = 0; d < 3; ++d)
    kmf16[((size_t)bn*3 + d)*128 + t] = (_Float16)(om[d] * (1.f/KNN));
}

// ---------------- V transpose (unchanged) ----------------
__global__ __launch_bounds__(256) void vtrans_kernel(const ushort_t* __restrict__ v,
                                                     ushort_t* __restrict__ vT) {
  int T = blockIdx.x * 256 + threadIdx.x;
  int pt0 = (T & 255) * 8;
  int row = T >> 8;
  int bh = row / 192, ch = row % 192;
  int b = bh / HH, h = bh % HH;
  int ol = ch / 3, dd = ch - 3*ol;
  size_t src = (size_t)dd*384 + h*64 + ol;
  ushort_t tmp[8];
#pragma unroll
  for (int i = 0; i < 8; ++i)
    tmp[i] = v[(size_t)(b*NFIX + pt0 + i)*1152 + src];
  uint4 o;
  o.x = (uint_t)tmp[0] | ((uint_t)tmp[1] << 16);
  o.y = (uint_t)tmp[2] | ((uint_t)tmp[3] << 16);
  o.z = (uint_t)tmp[4] | ((uint_t)tmp[5] << 16);
  o.w = (uint_t)tmp[6] | ((uint_t)tmp[7] << 16);
  *(uint4*)&vT[(size_t)row*2048 + pt0] = o;
}

// ---------------- attention v4: split-K=2 (grid 768 = exactly 3 blk/CU), odd LDS pitches
// (conflict-free), dbuf staging, shfl-P transpose, coalesced epilogue via per-wave LDS
// transpose into opart[n=(pt*3+dd)][h*64+ol]. ----------------
#define KT_P 194   // 97 dwords, gcd(97,32)=1 -> conflict-free fragment reads
#define VT_P 34    // 17 dwords, gcd(17,32)=1
#define TW_P 193   // epilogue tile pitch (fits in kt/vt quarters: 32*193 <= 32*194)
__global__ __launch_bounds__(256, 2) void attn_kernel(const ushort_t* __restrict__ q,
    const ushort_t* __restrict__ k, const ushort_t* __restrict__ vT,
    ushort_t* __restrict__ opart, float* __restrict__ lpart) {
  __shared__ ushort_t kt[2][32*KT_P];
  __shared__ ushort_t vt[2][192*VT_P];
  __shared__ float alds[4][32];
  int blk = blockIdx.x;
  int qt = blk % 16;
  int bh = (blk / 16) % 24;
  int split = blk / (16*24);          // 0..1
  int b = bh / HH, h = bh % HH;
  int t = threadIdx.x;
  int w = t >> 6, lane = t & 63, ql = lane & 31, hl = lane >> 5;
  int qrow0 = qt*128 + w*32;
  const ushort_t* qpb = q + (size_t)(b*NFIX + qrow0 + ql)*1152 + h*64;
  bf16x8 qf[12];
#pragma unroll
  for (int cs = 0; cs < 12; ++cs) {
    int red0 = cs*16 + hl*8;
    int dq = red0 >> 6, ml = red0 & 63;
    qf[cs] = *(const bf16x8*)(qpb + dq*384 + ml);
  }
  const ushort_t* ksrc[3]; int kdsto[3];
  const ushort_t* vsrc[3]; int vdsto[3];
#pragma unroll
  for (int j = 0; j < 3; ++j) {
    int idx = t + j*256;
    int kp = idx / 24, c16 = idx % 24;
    int red0 = c16*8;
    int dk = red0 >> 6, ml = red0 & 63;
    ksrc[j] = k + (size_t)(b*NFIX + kp)*1152 + dk*384 + h*64 + ml;
    kdsto[j] = kp*KT_P + c16*8;
    int ch = idx >> 2, c4 = idx & 3;
    vsrc[j] = vT + ((size_t)bh*192 + ch)*2048 + c4*8;
    vdsto[j] = ch*VT_P + c4*8;
  }
  f32x16 acc[6];
#pragma unroll
  for (int nt = 0; nt < 6; ++nt)
#pragma unroll
    for (int r = 0; r < 16; ++r) acc[nt][r] = 0.f;
  float lsum = 0.f;
  int koff0 = split * 1024;
  bf16x8 kpre[3], vpre[3];
#pragma unroll
  for (int j = 0; j < 3; ++j) {
    kpre[j] = *(const bf16x8*)(ksrc[j] + (size_t)koff0*1152);
    vpre[j] = *(const bf16x8*)(vsrc[j] + koff0);
  }
#pragma unroll
  for (int j = 0; j < 3; ++j) {
    ushort_t* kd = &kt[0][kdsto[j]];
    *(bf16x4*)kd = __builtin_shufflevector(kpre[j], kpre[j], 0, 1, 2, 3);
    *(bf16x4*)(kd+4) = __builtin_shufflevector(kpre[j], kpre[j], 4, 5, 6, 7);
    ushort_t* vd = &vt[0][vdsto[j]];
    *(bf16x4*)vd = __builtin_shufflevector(vpre[j], vpre[j], 0, 1, 2, 3);
    *(bf16x4*)(vd+4) = __builtin_shufflevector(vpre[j], vpre[j], 4, 5, 6, 7);
  }
  __syncthreads();
  for (int kb = 0; kb < 32; ++kb) {
    int cur = kb & 1;
    if (kb < 31) {
      int koff = koff0 + (kb+1)*32;
#pragma unroll
      for (int j = 0; j < 3; ++j) {
        kpre[j] = *(const bf16x8*)(ksrc[j] + (size_t)koff*1152);
        vpre[j] = *(const bf16x8*)(vsrc[j] + koff);
      }
    }
    f32x16 sc;
#pragma unroll
    for (int r = 0; r < 16; ++r) sc[r] = 0.f;
    const ushort_t* ktc = kt[cur];
#pragma unroll
    for (int cs = 0; cs < 12; ++cs) {
      const ushort_t* kr = &ktc[ql*KT_P + cs*16 + hl*8];
      bf16x4 alo = *(const bf16x4*)kr;
      bf16x4 ahi = *(const bf16x4*)(kr + 4);
      bf16x8 af = __builtin_shufflevector(alo, ahi, 0, 1, 2, 3, 4, 5, 6, 7);
      sc = __builtin_amdgcn_mfma_f32_32x32x16_bf16(af, qf[cs], sc, 0, 0, 0);
    }
    uint_t u[8], pex[8];
#pragma unroll
    for (int g2 = 0; g2 < 4; ++g2) {
      float p0 = __builtin_amdgcn_exp2f(sc[g2*4 + 0]);
      float p1 = __builtin_amdgcn_exp2f(sc[g2*4 + 1]);
      float p2 = __builtin_amdgcn_exp2f(sc[g2*4 + 2]);
      float p3 = __builtin_amdgcn_exp2f(sc[g2*4 + 3]);
      lsum += (p0 + p1) + (p2 + p3);
      u[2*g2]   = pack2(p0, p1);
      u[2*g2+1] = pack2(p2, p3);
    }
#pragma unroll
    for (int j = 0; j < 8; ++j) pex[j] = (uint_t)__shfl_xor((int)u[j], 32);
    const ushort_t* vtc = vt[cur];
#pragma unroll
    for (int s = 0; s < 2; ++s) {
      uint4 au;
      au.x = hl ? pex[4*s+2] : u[4*s+0];
      au.y = hl ? pex[4*s+3] : u[4*s+1];
      au.z = hl ? u[4*s+2]   : pex[4*s+0];
      au.w = hl ? u[4*s+3]   : pex[4*s+1];
      union { uint4 ui; bf16x8 bv; } cvt; cvt.ui = au;
      bf16x8 pa = cvt.bv;
#pragma unroll
      for (int nt = 0; nt < 6; ++nt) {
        const ushort_t* vr = &vtc[(nt*32 + ql)*VT_P + s*16 + hl*8];
        bf16x4 vlo = *(const bf16x4*)vr;
        bf16x4 vhi = *(const bf16x4*)(vr + 4);
        bf16x8 vf = __builtin_shufflevector(vlo, vhi, 0, 1, 2, 3, 4, 5, 6, 7);
        acc[nt] = __builtin_amdgcn_mfma_f32_32x32x16_bf16(pa, vf, acc[nt], 0, 0, 0);
      }
    }
    if (kb < 31) {
      int nxt = cur ^ 1;
#pragma unroll
      for (int j = 0; j < 3; ++j) {
        ushort_t* kd = &kt[nxt][kdsto[j]];
        *(bf16x4*)kd = __builtin_shufflevector(kpre[j], kpre[j], 0, 1, 2, 3);
        *(bf16x4*)(kd+4) = __builtin_shufflevector(kpre[j], kpre[j], 4, 5, 6, 7);
        ushort_t* vd = &vt[nxt][vdsto[j]];
        *(bf16x4*)vd = __builtin_shufflevector(vpre[j], vpre[j], 0, 1, 2, 3);
        *(bf16x4*)(vd+4) = __builtin_shufflevector(vpre[j], vpre[j], 4, 5, 6, 7);
      }
    }
    __syncthreads();
  }
  lsum += __shfl_xor(lsum, 32);
  if (lane < 32) {
    alds[w][ql] = 1.0f / lsum;
    lpart[(size_t)split*24*NFIX + (size_t)bh*NFIX + qrow0 + ql] = lsum;
  }
  asm volatile("s_waitcnt lgkmcnt(0)" ::: "memory");
  float lv[4][4];
#pragma unroll
  for (int g2 = 0; g2 < 4; ++g2) {
    f32x4 tv = *(const f32x4*)&alds[w][8*g2 + 4*hl];
#pragma unroll
    for (int rr = 0; rr < 4; ++rr) lv[g2][rr] = tv[rr];
  }
  // ---- coalesced epilogue: per-wave LDS transpose (private quarter; after final barrier) ----
  ushort_t* tw = (w == 0) ? kt[0] : (w == 1) ? kt[1] : (w == 2) ? vt[0] : vt[1];
#pragma unroll
  for (int nt = 0; nt < 6; ++nt) {
    int ch = nt*32 + ql;
#pragma unroll
    for (int r = 0; r < 16; ++r) {
      int qrow = (r&3) + 8*(r>>2) + 4*hl;
      tw[qrow*TW_P + ch] = f2bf(acc[nt][r] * lv[r>>2][r&3]);
    }
  }
  asm volatile("s_waitcnt lgkmcnt(0)" ::: "memory");
  const size_t SS = (size_t)8192*1152;
  ushort_t* opb = opart + (size_t)split*SS;
  size_t nbase = (size_t)(b*NFIX + qrow0) * 3;
#pragma unroll
  for (int i = 0; i < 12; ++i) {
    int chunk = i*64 + lane;
    int nl = chunk >> 3, jc = chunk & 7;
    int qq = nl / 3, dd = nl - 3*qq;
    ushort_t hv[8];
#pragma unroll
    for (int e = 0; e < 8; ++e)
      hv[e] = tw[qq*TW_P + (jc*8 + e)*3 + dd];
    uint4 sv;
    sv.x = (uint_t)hv[0] | ((uint_t)hv[1] << 16);
    sv.y = (uint_t)hv[2] | ((uint_t)hv[3] << 16);
    sv.z = (uint_t)hv[4] | ((uint_t)hv[5] << 16);
    sv.w = (uint_t)hv[6] | ((uint_t)hv[7] << 16);
    *(uint4*)&opb[(nbase + nl)*384 + h*64 + jc*8] = sv;
  }
}

// ---------------- x1mid fp16 MFMA: xmid[n][c] = xdi + [M|W2b] @ [o_comb|km], 2 splits ----------------
#define AP 68
__global__ __launch_bounds__(384) void x1mid_mfma(
    const float* __restrict__ xdi, const ushort_t* __restrict__ opart,
    const float* __restrict__ lpart, const _Float16* __restrict__ kmf16,
    const _Float16* __restrict__ Af16, float* __restrict__ xmid) {
  __shared__ __align__(16) char smem[33536];
  _Float16* As = (_Float16*)smem;                 // 128 x AP = 17408 B
  _Float16* Bt = (_Float16*)(smem + 17408);       //  96 x AP = 13056 B
  float* wlsL  = (float*)(smem + 30464);          //  32 x 6 x 2 = 1536 B
  float* trbase = (float*)smem;                   // epilogue overlay
  int blk = blockIdx.x;
  int n0 = blk * 96;
  int pt0 = blk * 32;
  int t = threadIdx.x;
  int w = t >> 6, lane = t & 63, ql = lane & 31, hl = lane >> 5;
  int nsub = w >> 1, mh = w & 1;
  if (t < 192) {
    int ptl = t / 6, h = t % 6;
    int ptg = pt0 + ptl;
    int b = ptg >> 11, n = ptg & 2047;
    size_t lidx = (size_t)(b*HH + h)*NFIX + n;
    float l0 = lpart[lidx];
    float l1 = lpart[(size_t)24*NFIX + lidx];
    float rd = 1.f / (l0 + l1);
    float* wp = &wlsL[(ptl*6 + h)*2];
    wp[0] = l0*rd; wp[1] = l1*rd;
  }
  f32x16 acc[2];
#pragma unroll
  for (int m2 = 0; m2 < 2; ++m2)
#pragma unroll
    for (int r = 0; r < 16; ++r) acc[m2][r] = 0.f;
  const size_t SS = (size_t)8192*1152;
  __syncthreads();
  for (int p = 0; p < 8; ++p) {
    for (int u = t; u < 1024; u += 384) {
      int m = u >> 3, kc = u & 7;
      f16x4 a0 = *(const f16x4*)&Af16[(size_t)m*512 + p*64 + kc*8];
      f16x4 a1 = *(const f16x4*)&Af16[(size_t)m*512 + p*64 + kc*8 + 4];
      _Float16* dst = &As[m*AP + kc*8];
      *(f16x4*)dst = a0;
      *(f16x4*)(dst+4) = a1;
    }
    {
      int u = t;
      if (u < 384) {
        int n_l = u >> 2, jc = u & 3;
        int n_g = n0 + n_l;
        _Float16* dst = &Bt[n_l*AP + jc*16];
        if (p < 6) {
          int pt_l = n_l / 3;
          const float* wp = &wlsL[(pt_l*6 + p)*2];
          float facc[16];
#pragma unroll
          for (int e = 0; e < 16; ++e) facc[e] = 0.f;
#pragma unroll
          for (int s = 0; s < 2; ++s) {
            const ushort_t* src = opart + s*SS + (size_t)n_g*384 + p*64 + jc*16;
            uint4 ra = *(const uint4*)src;
            uint4 rb = *(const uint4*)(src + 8);
            const ushort_t* ua = (const ushort_t*)&ra;
            const ushort_t* ub = (const ushort_t*)&rb;
            float wsc = wp[s];
#pragma unroll
            for (int e = 0; e < 8; ++e) {
              facc[e]     += wsc * bf2f(ua[e]);
              facc[8 + e] += wsc * bf2f(ub[e]);
            }
          }
          _Float16 hv[16];
#pragma unroll
          for (int e = 0; e < 16; ++e) hv[e] = (_Float16)facc[e];
#pragma unroll
          for (int g = 0; g < 4; ++g)
            *(f16x4*)(dst + g*4) = *(f16x4*)&hv[g*4];
        } else {
          const _Float16* src = kmf16 + (size_t)n_g*128 + (p-6)*64 + jc*16;
          f16x4 v0 = *(const f16x4*)src;
          f16x4 v1 = *(const f16x4*)(src + 4);
          f16x4 v2 = *(const f16x4*)(src + 8);
          f16x4 v3 = *(const f16x4*)(src + 12);
          *(f16x4*)dst = v0; *(f16x4*)(dst+4) = v1;
          *(f16x4*)(dst+8) = v2; *(f16x4*)(dst+12) = v3;
        }
      }
    }
    __syncthreads();
#pragma unroll
    for (int cs = 0; cs < 4; ++cs) {
      int kloc = cs*16 + hl*8;
      f16x4 b0 = *(const f16x4*)&Bt[(nsub*32 + ql)*AP + kloc];
      f16x4 b1 = *(const f16x4*)&Bt[(nsub*32 + ql)*AP + kloc + 4];
      f16x8 bf = __builtin_shufflevector(b0, b1, 0, 1, 2, 3, 4, 5, 6, 7);
#pragma unroll
      for (int m2 = 0; m2 < 2; ++m2) {
        int mrow = (mh*2 + m2)*32 + ql;
        f16x4 a0 = *(const f16x4*)&As[mrow*AP + kloc];
        f16x4 a1 = *(const f16x4*)&As[mrow*AP + kloc + 4];
        f16x8 af = __builtin_shufflevector(a0, a1, 0, 1, 2, 3, 4, 5, 6, 7);
        acc[m2] = __builtin_amdgcn_mfma_f32_32x32x16_f16(af, bf, acc[m2], 0, 0, 0);
      }
    }
    __syncthreads();
  }
  float* trw = trbase + w*32*34;
#pragma unroll
  for (int m2 = 0; m2 < 2; ++m2) {
#pragma unroll
    for (int r = 0; r < 16; ++r) {
      int mrow = (r&3) + 8*(r>>2) + 4*hl;
      trw[ql*34 + mrow] = acc[m2][r];
    }
    asm volatile("s_waitcnt lgkmcnt(0)" ::: "memory");
    float4 c0 = *(float4*)&trw[ql*34 + hl*16 + 0];
    float4 c1 = *(float4*)&trw[ql*34 + hl*16 + 4];
    float4 c2 = *(float4*)&trw[ql*34 + hl*16 + 8];
    float4 c3 = *(float4*)&trw[ql*34 + hl*16 + 12];
    asm volatile("s_waitcnt lgkmcnt(0)" ::: "memory");
    int n_g = n0 + nsub*32 + ql;
    int c0g = (mh*2 + m2)*32 + hl*16;
    const float* xd = xdi + (size_t)n_g*128 + c0g;
    float4 x0 = *(const float4*)xd;
    float4 x1 = *(const float4*)(xd + 4);
    float4 x2 = *(const float4*)(xd + 8);
    float4 x3 = *(const float4*)(xd + 12);
    c0.x += x0.x; c0.y += x0.y; c0.z += x0.z; c0.w += x0.w;
    c1.x += x1.x; c1.y += x1.y; c1.z += x1.z; c1.w += x1.w;
    c2.x += x2.x; c2.y += x2.y; c2.z += x2.z; c2.w += x2.w;
    c3.x += x3.x; c3.y += x3.y; c3.z += x3.z; c3.w += x3.w;
    float* dst = xmid + (size_t)n_g*128 + c0g;
    *(float4*)dst = c0;
    *(float4*)(dst + 4) = c1;
    *(float4*)(dst + 8) = c2;
    *(float4*)(dst + 12) = c3;
  }
}

// ---------------- conv3: VNLinearLeakyReLU 128 -> 256 (de-interleaved input) ----------------
__global__ __launch_bounds__(256) void conv3_kernel(const float* __restrict__ in,
    const float* __restrict__ W3t, const float* __restrict__ U3t,
    float* __restrict__ h3) {
  __shared__ float ins[4*384];
  int bnb = blockIdx.x * 4;
  int t = threadIdx.x;
  for (int idx = t; idx < 4*96; idx += 256)
    *(float4*)&ins[idx*4] = *(const float4*)&in[(size_t)bnb*384 + idx*4];
  __syncthreads();
  float p[4][3], dd[4][3];
#pragma unroll
  for (int pt = 0; pt < 4; ++pt)
#pragma unroll
    for (int d = 0; d < 3; ++d) { p[pt][d] = 0.f; dd[pt][d] = 0.f; }
  for (int ci = 0; ci < 32; ++ci) {
    float w3[4], u3[4];
#pragma unroll
    for (int cc = 0; cc < 4; ++cc) {
      int c = 4*ci + cc;
      w3[cc] = W3t[c*256 + t];
      u3[cc] = U3t[c*256 + t];
    }
#pragma unroll
    for (int pt = 0; pt < 4; ++pt) {
      const float* ip = &ins[pt*384 + 4*ci];
      float4 v0 = *(const float4*)ip;
      float4 v1 = *(const float4*)(ip + 128);
      float4 v2 = *(const float4*)(ip + 256);
      float vd[3][4] = {{v0.x,v0.y,v0.z,v0.w},{v1.x,v1.y,v1.z,v1.w},{v2.x,v2.y,v2.z,v2.w}};
#pragma unroll
      for (int cc = 0; cc < 4; ++cc)
#pragma unroll
        for (int d = 0; d < 3; ++d) {
          float xv = vd[d][cc];
          p[pt][d]  += w3[cc]*xv;
          dd[pt][d] += u3[cc]*xv;
        }
    }
  }
#pragma unroll
  for (int pt = 0; pt < 4; ++pt) {
    float res[3];
    vnleaky3(p[pt], dd[pt], res);
    size_t ob = ((size_t)bnb + pt)*768 + t*3;
    h3[ob+0] = res[0]; h3[ob+1] = res[1]; h3[ob+2] = res[2];
  }
}

// ---------------- conv4: VNLinearLeakyReLU 256 -> 128, + xmid residual -> standard-layout out ----------------
__global__ __launch_bounds__(128) void conv4_kernel(const float* __restrict__ h3,
    const float* __restrict__ W4t, const float* __restrict__ U4t,
    const float* __restrict__ xmid, float* __restrict__ out) {
  __shared__ float ins[4*768];
  int bnb = blockIdx.x * 4;
  int t = threadIdx.x;
  for (int idx = t; idx < 4*192; idx += 128)
    *(float4*)&ins[idx*4] = *(const float4*)&h3[(size_t)bnb*768 + idx*4];
  __syncthreads();
  float p[4][3], dd[4][3];
#pragma unroll
  for (int pt = 0; pt < 4; ++pt)
#pragma unroll
    for (int d = 0; d < 3; ++d) { p[pt][d] = 0.f; dd[pt][d] = 0.f; }
  for (int ci = 0; ci < 64; ++ci) {
    float w4[4], u4[4];
#pragma unroll
    for (int cc = 0; cc < 4; ++cc) {
      int c2 = 4*ci + cc;
      w4[cc] = W4t[c2*128 + t];
      u4[cc] = U4t[c2*128 + t];
    }
#pragma unroll
    for (int pt = 0; pt < 4; ++pt) {
      float vals[12];
      LOAD12(vals, &ins[pt*768 + 12*ci]);
#pragma unroll
      for (int cc = 0; cc < 4; ++cc)
#pragma unroll
        for (int d = 0; d < 3; ++d) {
          float xv = vals[cc*3+d];
          p[pt][d]  += w4[cc]*xv;
          dd[pt][d] += u4[cc]*xv;
        }
    }
  }
#pragma unroll
  for (int pt = 0; pt < 4; ++pt) {
    float res[3];
    vnleaky3(p[pt], dd[pt], res);
    size_t bn = (size_t)bnb + pt;
    float* orow = out + bn*384 + t*3;
#pragma unroll
    for (int d = 0; d < 3; ++d)
      orow[d] = res[d] + xmid[bn*384 + d*128 + t];
  }
}

extern "C" void kernel_launch(void* const* d_in, const int* in_sizes, int n_in,
                              void* d_out, int out_size, void* d_ws, size_t ws_size,
                              hipStream_t stream) {
  const float* x   = (const float*)d_in[0];
  const int* knn   = (const int*)d_in[1];
  const float* g1  = (const float*)d_in[2];
  const float* b1  = (const float*)d_in[3];
  const float* g2  = (const float*)d_in[4];
  const float* b2  = (const float*)d_in[5];
  const float* Wq  = (const float*)d_in[6];
  const float* Wk  = (const float*)d_in[7];
  const float* Wv  = (const float*)d_in[8];
  const float* Wo  = (const float*)d_in[9];
  const float* W1  = (const float*)d_in[10];
  const float* U1  = (const float*)d_in[11];
  const float* W2  = (const float*)d_in[12];
  const float* W3  = (const float*)d_in[13];
  const float* U3  = (const float*)d_in[14];
  const float* W4  = (const float*)d_in[15];
  const float* U4  = (const float*)d_in[16];
  float* out = (float*)d_out;
  (void)n_in; (void)out_size; (void)ws_size;

  const size_t BN = (size_t)in_sizes[0] / 384;   // 8192

  float* ws    = (float*)d_ws;
  float* xdi   = ws;                          // BN*384 f32 (raw x, de-interleaved [n][c])
  float* xmid  = xdi + BN*384;                // BN*384 f32 (x_mid, de-interleaved)
  _Float16* kmf16 = (_Float16*)(xmid + BN*384);  // BN*384 fp16 [n][128]
  ushort_t* xbp = (ushort_t*)(kmf16 + BN*384);   // BN*384 bf16 (LN1 normalized, de-interleaved)
  ushort_t* qb = xbp + BN*384;                // BN*1152 bf16
  ushort_t* kb = qb + BN*1152;
  ushort_t* vb = kb + BN*1152;
  ushort_t* vT = vb + BN*1152;
  ushort_t* Wall = vT + BN*1152;              // 212992 bf16
  _Float16* Af16 = (_Float16*)(Wall + 212992);   // 65536 fp16
  float* W3t  = (float*)(Af16 + 65536);
  float* U3t  = W3t + 32768;
  float* W4t  = U3t + 32768;
  float* U4t  = W4t + 32768;
  ushort_t* opart = (ushort_t*)(U4t + 32768); // region kept at 4*BN*1152 bf16 (2 splits used; aliasing)
  float* lpart = (float*)(opart + 4*BN*1152); // 2*24*2048 f32
  // YZf/NBf (BN*768 f32 each = 50 MB) alias the opart region: conv1_post runs before attn.
  float* YZf = (float*)opart;
  float* NBf = YZf + BN*768;
  float* nx2 = (float*)qb;   // q dead after x1mid
  float* h3  = (float*)kb;   // k+v dead after attention

  prep_weights<<<1600, 256, 0, stream>>>(Wq, Wk, Wv, Wo, W1, U1, W2, W3, U3, W4, U4,
                                         Wall, Af16, W3t, U3t, W4t, U4t);
  ln1_kernel<<<(int)BN, 128, 0, stream>>>(x, xbp, xdi, g1, b1);
  qkv_conv1_mfma<<<192*4, 256, 0, stream>>>(xbp, Wall, qb, kb, vb, YZf, NBf);
  conv1_post<<<(int)BN, 128, 0, stream>>>(YZf, NBf, knn, kmf16);
  vtrans_kernel<<<(int)(BN*1152/8/256), 256, 0, stream>>>(vb, vT);
  attn_kernel<<<16*24*2, 256, 0, stream>>>(qb, kb, vT, opart, lpart);
  x1mid_mfma<<<256, 384, 0, stream>>>(xdi, opart, lpart, kmf16, Af16, xmid);
  ln2_kernel<<<(int)BN, 128, 0, stream>>>(xmid, nx2, g2, b2);
  conv3_kernel<<<(int)(BN/4), 256, 0, stream>>>(nx2, W3t, U3t, h3);
  conv4_kernel<<<(int)(BN/4), 128, 0, stream>>>(h3, W4t, U4t, xmid, out);
}

// Round 11
// 472.347 us; speedup vs baseline: 2.0922x; 2.0922x over previous
//
#include <hip/hip_runtime.h>
#include <math.h>

// Problem constants (fixed by setup_inputs): B=4, N=2048, C=128, H=6, K=8
#define NFIX 2048
#define HH 6
#define KNN 8
#define NSLOPE 0.2f
#define EPSF 1e-6f
#define LNEPSF 1e-5f
// 0.125 (softmax scale) * log2(e), folded into Wq rows so S-MFMA output is exp2-ready
#define QSCALE 0.18033688011112042f

typedef unsigned short ushort_t;
typedef unsigned int uint_t;
typedef __attribute__((ext_vector_type(8))) short bf16x8;
typedef __attribute__((ext_vector_type(4))) short bf16x4;
typedef __attribute__((ext_vector_type(8))) _Float16 f16x8;
typedef __attribute__((ext_vector_type(4))) _Float16 f16x4;
typedef __attribute__((ext_vector_type(16))) float f32x16;
typedef __attribute__((ext_vector_type(4))) float f32x4;

__device__ __forceinline__ ushort_t f2bf(float f) {
  union { float f; unsigned u; } v; v.f = f;
  unsigned r = v.u + 0x7fff + ((v.u >> 16) & 1);   // RNE
  return (ushort_t)(r >> 16);
}
__device__ __forceinline__ float bf2f(ushort_t u) {
  union { uint_t u; float f; } v; v.u = ((uint_t)u) << 16; return v.f;
}
__device__ __forceinline__ uint_t pack2(float a, float b) {
  return (uint_t)f2bf(a) | ((uint_t)f2bf(b) << 16);
}

#define LOAD12(dst, ptr) { \
  float4 _r0 = *(const float4*)((ptr));   \
  float4 _r1 = *(const float4*)((ptr)+4); \
  float4 _r2 = *(const float4*)((ptr)+8); \
  dst[0]=_r0.x; dst[1]=_r0.y; dst[2]=_r0.z; dst[3]=_r0.w; \
  dst[4]=_r1.x; dst[5]=_r1.y; dst[6]=_r1.z; dst[7]=_r1.w; \
  dst[8]=_r2.x; dst[9]=_r2.y; dst[10]=_r2.z; dst[11]=_r2.w; }

__device__ __forceinline__ void vnleaky3(const float* p, const float* dv, float* out) {
  float dot = p[0]*dv[0] + p[1]*dv[1] + p[2]*dv[2];
  float dsq = dv[0]*dv[0] + dv[1]*dv[1] + dv[2]*dv[2] + EPSF;
  float f = dot / dsq;
#pragma unroll
  for (int d = 0; d < 3; ++d) {
    float neg = p[d] - f * dv[d];
    out[d] = NSLOPE * p[d] + (1.f - NSLOPE) * ((dot >= 0.f) ? p[d] : neg);
  }
}

// ---------------- weight prep ----------------
// Wall bf16 [1664][128] (qkv+conv1 GEMM A). Af16 fp16 [128][512] = [M2 | W2b] rows c.
// fp32: W3t | U3t | W4t | U4t.
__global__ void prep_weights(const float* __restrict__ Wq, const float* __restrict__ Wk,
                             const float* __restrict__ Wv, const float* __restrict__ Wo,
                             const float* __restrict__ W1, const float* __restrict__ U1,
                             const float* __restrict__ W2, const float* __restrict__ W3,
                             const float* __restrict__ U3, const float* __restrict__ W4,
                             const float* __restrict__ U4,
                             ushort_t* __restrict__ Wall, _Float16* __restrict__ Af16,
                             float* __restrict__ W3t, float* __restrict__ U3t,
                             float* __restrict__ W4t, float* __restrict__ U4t) {
  int idx = blockIdx.x * 256 + threadIdx.x;
  if (idx < 212992) {
    int m = idx >> 7, c = idx & 127;
    float val;
    if (m < 384)       val = Wq[m*128 + c] * QSCALE;
    else if (m < 768)  val = Wk[(m-384)*128 + c];
    else if (m < 1152) val = Wv[(m-768)*128 + c];
    else {
      int j = m - 1152;
      if (j < 128)      val = W1[j*256 + c];
      else if (j < 256) val = U1[(j-128)*256 + c];
      else if (j < 384) { int o = j-256; val = W1[o*256 + 128 + c] - W1[o*256 + c]; }
      else              { int o = j-384; val = U1[o*256 + 128 + c] - U1[o*256 + c]; }
    }
    Wall[idx] = f2bf(val); return;
  }
  idx -= 212992;
  if (idx < 49152) {
    int j = idx / 128, c = idx % 128;   // M2[c][j] = (W2a@Wo)[c][j]
    float s = 0.f;
    for (int cp = 0; cp < 128; ++cp) s += W2[c*256 + cp] * Wo[cp*384 + j];
    Af16[(size_t)c*512 + j] = (_Float16)s; return;
  }
  idx -= 49152;
  if (idx < 16384) {
    int c2 = idx / 128, c = idx % 128;
    Af16[(size_t)c*512 + 384 + c2] = (_Float16)W2[c*256 + 128 + c2]; return;
  }
  idx -= 16384;
  if (idx < 32768) { int c = idx / 256, o = idx % 256; W3t[idx] = W3[o*128 + c]; return; }
  idx -= 32768;
  if (idx < 32768) { int c = idx / 256, o = idx % 256; U3t[idx] = U3[o*128 + c]; return; }
  idx -= 32768;
  if (idx < 32768) { int c = idx / 128, o = idx % 128; W4t[idx] = W4[o*256 + c]; return; }
  idx -= 32768;
  if (idx < 32768) { int c = idx / 128, o = idx % 128; U4t[idx] = U4[o*256 + c]; return; }
}

// ---------------- LN1: raw x -> xbp (bf16 de-interleaved, normalized) + xdi (fp32 raw de-interleaved) ----------------
__global__ __launch_bounds__(128) void ln1_kernel(const float* __restrict__ in,
                                                  ushort_t* __restrict__ xbp,
                                                  float* __restrict__ xdi,
                                                  const float* __restrict__ g,
                                                  const float* __restrict__ b) {
  int bn = blockIdx.x;
  int c = threadIdx.x;
  const float* row = in + (size_t)bn * 384;
  float x0 = row[c*3+0], x1 = row[c*3+1], x2 = row[c*3+2];
  float nv = sqrtf(x0*x0 + x1*x1 + x2*x2 + EPSF);
  float s1 = nv, s2 = nv*nv;
#pragma unroll
  for (int off = 32; off >= 1; off >>= 1) {
    s1 += __shfl_down(s1, off);
    s2 += __shfl_down(s2, off);
  }
  __shared__ float red[4];
  int lane = threadIdx.x & 63, w = threadIdx.x >> 6;
  if (lane == 0) { red[w*2] = s1; red[w*2+1] = s2; }
  __syncthreads();
  float tot1 = red[0] + red[2], tot2 = red[1] + red[3];
  float mu  = tot1 * (1.f/128.f);
  float var = tot2 * (1.f/128.f) - mu*mu;
  float rsig = rsqrtf(var + LNEPSF);
  float nnew = g[c] * ((nv - mu) * rsig) + b[c];
  float sc = nnew / nv;
  size_t rb = (size_t)bn * 384;
  xbp[rb + c]       = f2bf(x0*sc);
  xbp[rb + 128 + c] = f2bf(x1*sc);
  xbp[rb + 256 + c] = f2bf(x2*sc);
  xdi[rb + c]       = x0;
  xdi[rb + 128 + c] = x1;
  xdi[rb + 256 + c] = x2;
}

// ---------------- LN2: de-interleaved fp32 in/out ----------------
__global__ __launch_bounds__(128) void ln2_kernel(const float* __restrict__ in,
                                                  float* __restrict__ out,
                                                  const float* __restrict__ g,
                                                  const float* __restrict__ b) {
  int bn = blockIdx.x;
  int c = threadIdx.x;
  size_t base = (size_t)bn * 384;
  float x0 = in[base + c], x1 = in[base + 128 + c], x2 = in[base + 256 + c];
  float nv = sqrtf(x0*x0 + x1*x1 + x2*x2 + EPSF);
  float s1 = nv, s2 = nv*nv;
#pragma unroll
  for (int off = 32; off >= 1; off >>= 1) {
    s1 += __shfl_down(s1, off);
    s2 += __shfl_down(s2, off);
  }
  __shared__ float red[4];
  int lane = threadIdx.x & 63, w = threadIdx.x >> 6;
  if (lane == 0) { red[w*2] = s1; red[w*2+1] = s2; }
  __syncthreads();
  float tot1 = red[0] + red[2], tot2 = red[1] + red[3];
  float mu  = tot1 * (1.f/128.f);
  float var = tot2 * (1.f/128.f) - mu*mu;
  float rsig = rsqrtf(var + LNEPSF);
  float nnew = g[c] * ((nv - mu) * rsig) + b[c];
  float sc = nnew / nv;
  out[base + c]       = x0*sc;
  out[base + 128 + c] = x1*sc;
  out[base + 256 + c] = x2*sc;
}

// ---------------- fused QKV + conv1 MFMA GEMM (unchanged) ----------------
#define XT_PITCH 132
#define WT_PITCH 132
#define TR_PITCH 36
__global__ __launch_bounds__(256, 2) void qkv_conv1_mfma(
    const ushort_t* __restrict__ xb, const ushort_t* __restrict__ Wall,
    ushort_t* __restrict__ q, ushort_t* __restrict__ k, ushort_t* __restrict__ v,
    float* __restrict__ YZf, float* __restrict__ NBf) {
  __shared__ ushort_t xs[128*XT_PITCH];
  __shared__ ushort_t wt[32*WT_PITCH];
  __shared__ float tr[4][32*TR_PITCH];
  int nb = blockIdx.x % 192;
  int mq = blockIdx.x / 192;
  int n0 = nb * 128;
  int t = threadIdx.x;
  int w = t >> 6, lane = t & 63, ql = lane & 31, hl = lane >> 5;
  for (int idx = t; idx < 2048; idx += 256) {
    int n = idx >> 4, c16 = idx & 15;
    bf16x8 gv = *(const bf16x8*)&xb[(size_t)(n0 + n)*128 + c16*8];
    ushort_t* dst = &xs[n*XT_PITCH + c16*8];
    *(bf16x4*)dst = __builtin_shufflevector(gv, gv, 0, 1, 2, 3);
    *(bf16x4*)(dst+4) = __builtin_shufflevector(gv, gv, 4, 5, 6, 7);
  }
  __syncthreads();
  bf16x8 xf[8];
  {
    const ushort_t* xr = &xs[(w*32 + ql)*XT_PITCH + hl*8];
#pragma unroll
    for (int cs = 0; cs < 8; ++cs) {
      bf16x4 lo = *(const bf16x4*)(xr + cs*16);
      bf16x4 hi = *(const bf16x4*)(xr + cs*16 + 4);
      xf[cs] = __builtin_shufflevector(lo, hi, 0, 1, 2, 3, 4, 5, 6, 7);
    }
  }
  int ng = n0 + w*32 + ql;
  int pt = ng / 3;
  int d  = ng - 3*pt;
  float* trw = tr[w];
  for (int mt = 0; mt < 13; ++mt) {
    int m0 = mq*416 + mt*32;
    __syncthreads();
    for (int idx = t; idx < 512; idx += 256) {
      int mm = idx >> 4, c16 = idx & 15;
      bf16x8 gv = *(const bf16x8*)&Wall[(size_t)(m0 + mm)*128 + c16*8];
      ushort_t* dst = &wt[mm*WT_PITCH + c16*8];
      *(bf16x4*)dst = __builtin_shufflevector(gv, gv, 0, 1, 2, 3);
      *(bf16x4*)(dst+4) = __builtin_shufflevector(gv, gv, 4, 5, 6, 7);
    }
    __syncthreads();
    f32x16 acc;
#pragma unroll
    for (int r = 0; r < 16; ++r) acc[r] = 0.f;
    const ushort_t* wr = &wt[ql*WT_PITCH + hl*8];
#pragma unroll
    for (int cs = 0; cs < 8; ++cs) {
      bf16x4 lo = *(const bf16x4*)(wr + cs*16);
      bf16x4 hi = *(const bf16x4*)(wr + cs*16 + 4);
      bf16x8 af = __builtin_shufflevector(lo, hi, 0, 1, 2, 3, 4, 5, 6, 7);
      acc = __builtin_amdgcn_mfma_f32_32x32x16_bf16(af, xf[cs], acc, 0, 0, 0);
    }
#pragma unroll
    for (int r = 0; r < 16; ++r) {
      int mrow = (r&3) + 8*(r>>2) + 4*hl;
      trw[ql*TR_PITCH + mrow] = acc[r];
    }
    asm volatile("s_waitcnt lgkmcnt(0)" ::: "memory");
    float4 c0 = *(float4*)&trw[ql*TR_PITCH + hl*16 + 0];
    float4 c1 = *(float4*)&trw[ql*TR_PITCH + hl*16 + 4];
    float4 c2 = *(float4*)&trw[ql*TR_PITCH + hl*16 + 8];
    float4 c3 = *(float4*)&trw[ql*TR_PITCH + hl*16 + 12];
    asm volatile("s_waitcnt lgkmcnt(0)" ::: "memory");
    int mg = m0 + hl*16;
    if (m0 < 1152) {
      uint4 s0, s1;
      s0.x = pack2(c0.x, c0.y); s0.y = pack2(c0.z, c0.w);
      s0.z = pack2(c1.x, c1.y); s0.w = pack2(c1.z, c1.w);
      s1.x = pack2(c2.x, c2.y); s1.y = pack2(c2.z, c2.w);
      s1.z = pack2(c3.x, c3.y); s1.w = pack2(c3.z, c3.w);
      ushort_t* dst;
      if (m0 < 384)       dst = q + (size_t)pt*1152 + d*384 + mg;
      else if (m0 < 768)  dst = k + (size_t)pt*1152 + d*384 + (mg - 384);
      else                dst = v + (size_t)pt*1152 + d*384 + (mg - 768);
      *(uint4*)dst = s0;
      *(uint4*)(dst + 8) = s1;
    } else {
      int mat = mg - 1152;
      int sub = mat >> 7, o = mat & 127;
      float* base = (sub < 2) ? YZf : NBf;
      float* dst = base + (size_t)pt*768 + d*256 + (sub & 1)*128 + o;
      *(float4*)dst = c0;
      *(float4*)(dst + 4) = c1;
      *(float4*)(dst + 8) = c2;
      *(float4*)(dst + 12) = c3;
    }
  }
}

// ---------------- conv1 post: gather + vnleaky + mean -> kmf16 [n=(pt*3+d)][o] fp16 ----------------
__global__ __launch_bounds__(128) void conv1_post(const float* __restrict__ YZf,
    const float* __restrict__ NBf, const int* __restrict__ knn_index,
    _Float16* __restrict__ kmf16) {
  int bn = blockIdx.x;
  int b = bn / NFIX, n = bn % NFIX;
  int t = threadIdx.x;
  __shared__ int sidx[KNN];
  if (t < KNN) sidx[t] = knn_index[(b*KNN + t)*NFIX + n];
  __syncthreads();
  float yb[3], zb[3];
#pragma unroll
  for (int d = 0; d < 3; ++d) {
    yb[d] = NBf[(size_t)bn*768 + d*256 + t];
    zb[d] = NBf[(size_t)bn*768 + d*256 + 128 + t];
  }
  float om[3] = {0.f, 0.f, 0.f};
#pragma unroll
  for (int kk = 0; kk < KNN; ++kk) {
    const float* r = YZf + (size_t)sidx[kk]*768;
    float p[3], dd[3];
#pragma unroll
    for (int d = 0; d < 3; ++d) {
      p[d]  = r[d*256 + t] + yb[d];
      dd[d] = r[d*256 + 128 + t] + zb[d];
    }
    float res[3];
    vnleaky3(p, dd, res);
    om[0] += res[0]; om[1] += res[1]; om[2] += res[2];
  }
#pragma unroll
  for (int d = 0; d < 3; ++d)
    kmf16[((size_t)bn*3 + d)*128 + t] = (_Float16)(om[d] * (1.f/KNN));
}

// ---------------- V transpose (unchanged) ----------------
__global__ __launch_bounds__(256) void vtrans_kernel(const ushort_t* __restrict__ v,
                                                     ushort_t* __restrict__ vT) {
  int T = blockIdx.x * 256 + threadIdx.x;
  int pt0 = (T & 255) * 8;
  int row = T >> 8;
  int bh = row / 192, ch = row % 192;
  int b = bh / HH, h = bh % HH;
  int ol = ch / 3, dd = ch - 3*ol;
  size_t src = (size_t)dd*384 + h*64 + ol;
  ushort_t tmp[8];
#pragma unroll
  for (int i = 0; i < 8; ++i)
    tmp[i] = v[(size_t)(b*NFIX + pt0 + i)*1152 + src];
  uint4 o;
  o.x = (uint_t)tmp[0] | ((uint_t)tmp[1] << 16);
  o.y = (uint_t)tmp[2] | ((uint_t)tmp[3] << 16);
  o.z = (uint_t)tmp[4] | ((uint_t)tmp[5] << 16);
  o.w = (uint_t)tmp[6] | ((uint_t)tmp[7] << 16);
  *(uint4*)&vT[(size_t)row*2048 + pt0] = o;
}

// ---------------- attention v5: split-K=2, 8-BYTE-ALIGNED LDS pitches (196/36: r10's odd
// pitches 194/34 made every b64 DS op misaligned -> 4x slowdown), dbuf staging, shfl-P
// transpose, coalesced epilogue via per-wave b16 LDS transpose (odd pitch OK for b16). ----------------
#define KT_P 196   // 392 B rows: 8B-aligned; 98-dword stride -> 2-way bank aliasing (free, m136)
#define VT_P 36    // 72 B rows: aligned; 18-dword stride -> 2-way (free)
#define TW_P 195   // epilogue b16 transpose pitch (b16 has no 8B alignment requirement)
__global__ __launch_bounds__(256, 2) void attn_kernel(const ushort_t* __restrict__ q,
    const ushort_t* __restrict__ k, const ushort_t* __restrict__ vT,
    ushort_t* __restrict__ opart, float* __restrict__ lpart) {
  __shared__ ushort_t kt[2][32*KT_P];
  __shared__ ushort_t vt[2][192*VT_P];
  __shared__ float alds[4][32];
  int blk = blockIdx.x;
  int qt = blk % 16;
  int bh = (blk / 16) % 24;
  int split = blk / (16*24);          // 0..1
  int b = bh / HH, h = bh % HH;
  int t = threadIdx.x;
  int w = t >> 6, lane = t & 63, ql = lane & 31, hl = lane >> 5;
  int qrow0 = qt*128 + w*32;
  const ushort_t* qpb = q + (size_t)(b*NFIX + qrow0 + ql)*1152 + h*64;
  bf16x8 qf[12];
#pragma unroll
  for (int cs = 0; cs < 12; ++cs) {
    int red0 = cs*16 + hl*8;
    int dq = red0 >> 6, ml = red0 & 63;
    qf[cs] = *(const bf16x8*)(qpb + dq*384 + ml);
  }
  const ushort_t* ksrc[3]; int kdsto[3];
  const ushort_t* vsrc[3]; int vdsto[3];
#pragma unroll
  for (int j = 0; j < 3; ++j) {
    int idx = t + j*256;
    int kp = idx / 24, c16 = idx % 24;
    int red0 = c16*8;
    int dk = red0 >> 6, ml = red0 & 63;
    ksrc[j] = k + (size_t)(b*NFIX + kp)*1152 + dk*384 + h*64 + ml;
    kdsto[j] = kp*KT_P + c16*8;
    int ch = idx >> 2, c4 = idx & 3;
    vsrc[j] = vT + ((size_t)bh*192 + ch)*2048 + c4*8;
    vdsto[j] = ch*VT_P + c4*8;
  }
  f32x16 acc[6];
#pragma unroll
  for (int nt = 0; nt < 6; ++nt)
#pragma unroll
    for (int r = 0; r < 16; ++r) acc[nt][r] = 0.f;
  float lsum = 0.f;
  int koff0 = split * 1024;
  bf16x8 kpre[3], vpre[3];
#pragma unroll
  for (int j = 0; j < 3; ++j) {
    kpre[j] = *(const bf16x8*)(ksrc[j] + (size_t)koff0*1152);
    vpre[j] = *(const bf16x8*)(vsrc[j] + koff0);
  }
#pragma unroll
  for (int j = 0; j < 3; ++j) {
    ushort_t* kd = &kt[0][kdsto[j]];
    *(bf16x4*)kd = __builtin_shufflevector(kpre[j], kpre[j], 0, 1, 2, 3);
    *(bf16x4*)(kd+4) = __builtin_shufflevector(kpre[j], kpre[j], 4, 5, 6, 7);
    ushort_t* vd = &vt[0][vdsto[j]];
    *(bf16x4*)vd = __builtin_shufflevector(vpre[j], vpre[j], 0, 1, 2, 3);
    *(bf16x4*)(vd+4) = __builtin_shufflevector(vpre[j], vpre[j], 4, 5, 6, 7);
  }
  __syncthreads();
  for (int kb = 0; kb < 32; ++kb) {
    int cur = kb & 1;
    if (kb < 31) {
      int koff = koff0 + (kb+1)*32;
#pragma unroll
      for (int j = 0; j < 3; ++j) {
        kpre[j] = *(const bf16x8*)(ksrc[j] + (size_t)koff*1152);
        vpre[j] = *(const bf16x8*)(vsrc[j] + koff);
      }
    }
    f32x16 sc;
#pragma unroll
    for (int r = 0; r < 16; ++r) sc[r] = 0.f;
    const ushort_t* ktc = kt[cur];
#pragma unroll
    for (int cs = 0; cs < 12; ++cs) {
      const ushort_t* kr = &ktc[ql*KT_P + cs*16 + hl*8];
      bf16x4 alo = *(const bf16x4*)kr;
      bf16x4 ahi = *(const bf16x4*)(kr + 4);
      bf16x8 af = __builtin_shufflevector(alo, ahi, 0, 1, 2, 3, 4, 5, 6, 7);
      sc = __builtin_amdgcn_mfma_f32_32x32x16_bf16(af, qf[cs], sc, 0, 0, 0);
    }
    uint_t u[8], pex[8];
#pragma unroll
    for (int g2 = 0; g2 < 4; ++g2) {
      float p0 = __builtin_amdgcn_exp2f(sc[g2*4 + 0]);
      float p1 = __builtin_amdgcn_exp2f(sc[g2*4 + 1]);
      float p2 = __builtin_amdgcn_exp2f(sc[g2*4 + 2]);
      float p3 = __builtin_amdgcn_exp2f(sc[g2*4 + 3]);
      lsum += (p0 + p1) + (p2 + p3);
      u[2*g2]   = pack2(p0, p1);
      u[2*g2+1] = pack2(p2, p3);
    }
#pragma unroll
    for (int j = 0; j < 8; ++j) pex[j] = (uint_t)__shfl_xor((int)u[j], 32);
    const ushort_t* vtc = vt[cur];
#pragma unroll
    for (int s = 0; s < 2; ++s) {
      uint4 au;
      au.x = hl ? pex[4*s+2] : u[4*s+0];
      au.y = hl ? pex[4*s+3] : u[4*s+1];
      au.z = hl ? u[4*s+2]   : pex[4*s+0];
      au.w = hl ? u[4*s+3]   : pex[4*s+1];
      union { uint4 ui; bf16x8 bv; } cvt; cvt.ui = au;
      bf16x8 pa = cvt.bv;
#pragma unroll
      for (int nt = 0; nt < 6; ++nt) {
        const ushort_t* vr = &vtc[(nt*32 + ql)*VT_P + s*16 + hl*8];
        bf16x4 vlo = *(const bf16x4*)vr;
        bf16x4 vhi = *(const bf16x4*)(vr + 4);
        bf16x8 vf = __builtin_shufflevector(vlo, vhi, 0, 1, 2, 3, 4, 5, 6, 7);
        acc[nt] = __builtin_amdgcn_mfma_f32_32x32x16_bf16(pa, vf, acc[nt], 0, 0, 0);
      }
    }
    if (kb < 31) {
      int nxt = cur ^ 1;
#pragma unroll
      for (int j = 0; j < 3; ++j) {
        ushort_t* kd = &kt[nxt][kdsto[j]];
        *(bf16x4*)kd = __builtin_shufflevector(kpre[j], kpre[j], 0, 1, 2, 3);
        *(bf16x4*)(kd+4) = __builtin_shufflevector(kpre[j], kpre[j], 4, 5, 6, 7);
        ushort_t* vd = &vt[nxt][vdsto[j]];
        *(bf16x4*)vd = __builtin_shufflevector(vpre[j], vpre[j], 0, 1, 2, 3);
        *(bf16x4*)(vd+4) = __builtin_shufflevector(vpre[j], vpre[j], 4, 5, 6, 7);
      }
    }
    __syncthreads();
  }
  lsum += __shfl_xor(lsum, 32);
  if (lane < 32) {
    alds[w][ql] = 1.0f / lsum;
    lpart[(size_t)split*24*NFIX + (size_t)bh*NFIX + qrow0 + ql] = lsum;
  }
  asm volatile("s_waitcnt lgkmcnt(0)" ::: "memory");
  float lv[4][4];
#pragma unroll
  for (int g2 = 0; g2 < 4; ++g2) {
    f32x4 tv = *(const f32x4*)&alds[w][8*g2 + 4*hl];
#pragma unroll
    for (int rr = 0; rr < 4; ++rr) lv[g2][rr] = tv[rr];
  }
  // ---- coalesced epilogue: per-wave b16 LDS transpose (private quarter; after final barrier) ----
  ushort_t* tw = (w == 0) ? kt[0] : (w == 1) ? kt[1] : (w == 2) ? vt[0] : vt[1];
#pragma unroll
  for (int nt = 0; nt < 6; ++nt) {
    int ch = nt*32 + ql;
#pragma unroll
    for (int r = 0; r < 16; ++r) {
      int qrow = (r&3) + 8*(r>>2) + 4*hl;
      tw[qrow*TW_P + ch] = f2bf(acc[nt][r] * lv[r>>2][r&3]);
    }
  }
  asm volatile("s_waitcnt lgkmcnt(0)" ::: "memory");
  const size_t SS = (size_t)8192*1152;
  ushort_t* opb = opart + (size_t)split*SS;
  size_t nbase = (size_t)(b*NFIX + qrow0) * 3;
#pragma unroll
  for (int i = 0; i < 12; ++i) {
    int chunk = i*64 + lane;
    int nl = chunk >> 3, jc = chunk & 7;
    int qq = nl / 3, dd = nl - 3*qq;
    ushort_t hv[8];
#pragma unroll
    for (int e = 0; e < 8; ++e)
      hv[e] = tw[qq*TW_P + (jc*8 + e)*3 + dd];
    uint4 sv;
    sv.x = (uint_t)hv[0] | ((uint_t)hv[1] << 16);
    sv.y = (uint_t)hv[2] | ((uint_t)hv[3] << 16);
    sv.z = (uint_t)hv[4] | ((uint_t)hv[5] << 16);
    sv.w = (uint_t)hv[6] | ((uint_t)hv[7] << 16);
    *(uint4*)&opb[(nbase + nl)*384 + h*64 + jc*8] = sv;
  }
}

// ---------------- x1mid fp16 MFMA: xmid[n][c] = xdi + [M|W2b] @ [o_comb|km], 2 splits ----------------
#define AP 68
__global__ __launch_bounds__(384) void x1mid_mfma(
    const float* __restrict__ xdi, const ushort_t* __restrict__ opart,
    const float* __restrict__ lpart, const _Float16* __restrict__ kmf16,
    const _Float16* __restrict__ Af16, float* __restrict__ xmid) {
  __shared__ __align__(16) char smem[33536];
  _Float16* As = (_Float16*)smem;                 // 128 x AP = 17408 B
  _Float16* Bt = (_Float16*)(smem + 17408);       //  96 x AP = 13056 B
  float* wlsL  = (float*)(smem + 30464);          //  32 x 6 x 2 = 1536 B
  float* trbase = (float*)smem;                   // epilogue overlay
  int blk = blockIdx.x;
  int n0 = blk * 96;
  int pt0 = blk * 32;
  int t = threadIdx.x;
  int w = t >> 6, lane = t & 63, ql = lane & 31, hl = lane >> 5;
  int nsub = w >> 1, mh = w & 1;
  if (t < 192) {
    int ptl = t / 6, h = t % 6;
    int ptg = pt0 + ptl;
    int b = ptg >> 11, n = ptg & 2047;
    size_t lidx = (size_t)(b*HH + h)*NFIX + n;
    float l0 = lpart[lidx];
    float l1 = lpart[(size_t)24*NFIX + lidx];
    float rd = 1.f / (l0 + l1);
    float* wp = &wlsL[(ptl*6 + h)*2];
    wp[0] = l0*rd; wp[1] = l1*rd;
  }
  f32x16 acc[2];
#pragma unroll
  for (int m2 = 0; m2 < 2; ++m2)
#pragma unroll
    for (int r = 0; r < 16; ++r) acc[m2][r] = 0.f;
  const size_t SS = (size_t)8192*1152;
  __syncthreads();
  for (int p = 0; p < 8; ++p) {
    for (int u = t; u < 1024; u += 384) {
      int m = u >> 3, kc = u & 7;
      f16x4 a0 = *(const f16x4*)&Af16[(size_t)m*512 + p*64 + kc*8];
      f16x4 a1 = *(const f16x4*)&Af16[(size_t)m*512 + p*64 + kc*8 + 4];
      _Float16* dst = &As[m*AP + kc*8];
      *(f16x4*)dst = a0;
      *(f16x4*)(dst+4) = a1;
    }
    {
      int u = t;
      if (u < 384) {
        int n_l = u >> 2, jc = u & 3;
        int n_g = n0 + n_l;
        _Float16* dst = &Bt[n_l*AP + jc*16];
        if (p < 6) {
          int pt_l = n_l / 3;
          const float* wp = &wlsL[(pt_l*6 + p)*2];
          float facc[16];
#pragma unroll
          for (int e = 0; e < 16; ++e) facc[e] = 0.f;
#pragma unroll
          for (int s = 0; s < 2; ++s) {
            const ushort_t* src = opart + s*SS + (size_t)n_g*384 + p*64 + jc*16;
            uint4 ra = *(const uint4*)src;
            uint4 rb = *(const uint4*)(src + 8);
            const ushort_t* ua = (const ushort_t*)&ra;
            const ushort_t* ub = (const ushort_t*)&rb;
            float wsc = wp[s];
#pragma unroll
            for (int e = 0; e < 8; ++e) {
              facc[e]     += wsc * bf2f(ua[e]);
              facc[8 + e] += wsc * bf2f(ub[e]);
            }
          }
          _Float16 hv[16];
#pragma unroll
          for (int e = 0; e < 16; ++e) hv[e] = (_Float16)facc[e];
#pragma unroll
          for (int g = 0; g < 4; ++g)
            *(f16x4*)(dst + g*4) = *(f16x4*)&hv[g*4];
        } else {
          const _Float16* src = kmf16 + (size_t)n_g*128 + (p-6)*64 + jc*16;
          f16x4 v0 = *(const f16x4*)src;
          f16x4 v1 = *(const f16x4*)(src + 4);
          f16x4 v2 = *(const f16x4*)(src + 8);
          f16x4 v3 = *(const f16x4*)(src + 12);
          *(f16x4*)dst = v0; *(f16x4*)(dst+4) = v1;
          *(f16x4*)(dst+8) = v2; *(f16x4*)(dst+12) = v3;
        }
      }
    }
    __syncthreads();
#pragma unroll
    for (int cs = 0; cs < 4; ++cs) {
      int kloc = cs*16 + hl*8;
      f16x4 b0 = *(const f16x4*)&Bt[(nsub*32 + ql)*AP + kloc];
      f16x4 b1 = *(const f16x4*)&Bt[(nsub*32 + ql)*AP + kloc + 4];
      f16x8 bf = __builtin_shufflevector(b0, b1, 0, 1, 2, 3, 4, 5, 6, 7);
#pragma unroll
      for (int m2 = 0; m2 < 2; ++m2) {
        int mrow = (mh*2 + m2)*32 + ql;
        f16x4 a0 = *(const f16x4*)&As[mrow*AP + kloc];
        f16x4 a1 = *(const f16x4*)&As[mrow*AP + kloc + 4];
        f16x8 af = __builtin_shufflevector(a0, a1, 0, 1, 2, 3, 4, 5, 6, 7);
        acc[m2] = __builtin_amdgcn_mfma_f32_32x32x16_f16(af, bf, acc[m2], 0, 0, 0);
      }
    }
    __syncthreads();
  }
  float* trw = trbase + w*32*34;
#pragma unroll
  for (int m2 = 0; m2 < 2; ++m2) {
#pragma unroll
    for (int r = 0; r < 16; ++r) {
      int mrow = (r&3) + 8*(r>>2) + 4*hl;
      trw[ql*34 + mrow] = acc[m2][r];
    }
    asm volatile("s_waitcnt lgkmcnt(0)" ::: "memory");
    float4 c0 = *(float4*)&trw[ql*34 + hl*16 + 0];
    float4 c1 = *(float4*)&trw[ql*34 + hl*16 + 4];
    float4 c2 = *(float4*)&trw[ql*34 + hl*16 + 8];
    float4 c3 = *(float4*)&trw[ql*34 + hl*16 + 12];
    asm volatile("s_waitcnt lgkmcnt(0)" ::: "memory");
    int n_g = n0 + nsub*32 + ql;
    int c0g = (mh*2 + m2)*32 + hl*16;
    const float* xd = xdi + (size_t)n_g*128 + c0g;
    float4 x0 = *(const float4*)xd;
    float4 x1 = *(const float4*)(xd + 4);
    float4 x2 = *(const float4*)(xd + 8);
    float4 x3 = *(const float4*)(xd + 12);
    c0.x += x0.x; c0.y += x0.y; c0.z += x0.z; c0.w += x0.w;
    c1.x += x1.x; c1.y += x1.y; c1.z += x1.z; c1.w += x1.w;
    c2.x += x2.x; c2.y += x2.y; c2.z += x2.z; c2.w += x2.w;
    c3.x += x3.x; c3.y += x3.y; c3.z += x3.z; c3.w += x3.w;
    float* dst = xmid + (size_t)n_g*128 + c0g;
    *(float4*)dst = c0;
    *(float4*)(dst + 4) = c1;
    *(float4*)(dst + 8) = c2;
    *(float4*)(dst + 12) = c3;
  }
}

// ---------------- conv3: VNLinearLeakyReLU 128 -> 256 (de-interleaved input) ----------------
__global__ __launch_bounds__(256) void conv3_kernel(const float* __restrict__ in,
    const float* __restrict__ W3t, const float* __restrict__ U3t,
    float* __restrict__ h3) {
  __shared__ float ins[4*384];
  int bnb = blockIdx.x * 4;
  int t = threadIdx.x;
  for (int idx = t; idx < 4*96; idx += 256)
    *(float4*)&ins[idx*4] = *(const float4*)&in[(size_t)bnb*384 + idx*4];
  __syncthreads();
  float p[4][3], dd[4][3];
#pragma unroll
  for (int pt = 0; pt < 4; ++pt)
#pragma unroll
    for (int d = 0; d < 3; ++d) { p[pt][d] = 0.f; dd[pt][d] = 0.f; }
  for (int ci = 0; ci < 32; ++ci) {
    float w3[4], u3[4];
#pragma unroll
    for (int cc = 0; cc < 4; ++cc) {
      int c = 4*ci + cc;
      w3[cc] = W3t[c*256 + t];
      u3[cc] = U3t[c*256 + t];
    }
#pragma unroll
    for (int pt = 0; pt < 4; ++pt) {
      const float* ip = &ins[pt*384 + 4*ci];
      float4 v0 = *(const float4*)ip;
      float4 v1 = *(const float4*)(ip + 128);
      float4 v2 = *(const float4*)(ip + 256);
      float vd[3][4] = {{v0.x,v0.y,v0.z,v0.w},{v1.x,v1.y,v1.z,v1.w},{v2.x,v2.y,v2.z,v2.w}};
#pragma unroll
      for (int cc = 0; cc < 4; ++cc)
#pragma unroll
        for (int d = 0; d < 3; ++d) {
          float xv = vd[d][cc];
          p[pt][d]  += w3[cc]*xv;
          dd[pt][d] += u3[cc]*xv;
        }
    }
  }
#pragma unroll
  for (int pt = 0; pt < 4; ++pt) {
    float res[3];
    vnleaky3(p[pt], dd[pt], res);
    size_t ob = ((size_t)bnb + pt)*768 + t*3;
    h3[ob+0] = res[0]; h3[ob+1] = res[1]; h3[ob+2] = res[2];
  }
}

// ---------------- conv4: VNLinearLeakyReLU 256 -> 128, + xmid residual -> standard-layout out ----------------
__global__ __launch_bounds__(128) void conv4_kernel(const float* __restrict__ h3,
    const float* __restrict__ W4t, const float* __restrict__ U4t,
    const float* __restrict__ xmid, float* __restrict__ out) {
  __shared__ float ins[4*768];
  int bnb = blockIdx.x * 4;
  int t = threadIdx.x;
  for (int idx = t; idx < 4*192; idx += 128)
    *(float4*)&ins[idx*4] = *(const float4*)&h3[(size_t)bnb*768 + idx*4];
  __syncthreads();
  float p[4][3], dd[4][3];
#pragma unroll
  for (int pt = 0; pt < 4; ++pt)
#pragma unroll
    for (int d = 0; d < 3; ++d) { p[pt][d] = 0.f; dd[pt][d] = 0.f; }
  for (int ci = 0; ci < 64; ++ci) {
    float w4[4], u4[4];
#pragma unroll
    for (int cc = 0; cc < 4; ++cc) {
      int c2 = 4*ci + cc;
      w4[cc] = W4t[c2*128 + t];
      u4[cc] = U4t[c2*128 + t];
    }
#pragma unroll
    for (int pt = 0; pt < 4; ++pt) {
      float vals[12];
      LOAD12(vals, &ins[pt*768 + 12*ci]);
#pragma unroll
      for (int cc = 0; cc < 4; ++cc)
#pragma unroll
        for (int d = 0; d < 3; ++d) {
          float xv = vals[cc*3+d];
          p[pt][d]  += w4[cc]*xv;
          dd[pt][d] += u4[cc]*xv;
        }
    }
  }
#pragma unroll
  for (int pt = 0; pt < 4; ++pt) {
    float res[3];
    vnleaky3(p[pt], dd[pt], res);
    size_t bn = (size_t)bnb + pt;
    float* orow = out + bn*384 + t*3;
#pragma unroll
    for (int d = 0; d < 3; ++d)
      orow[d] = res[d] + xmid[bn*384 + d*128 + t];
  }
}

extern "C" void kernel_launch(void* const* d_in, const int* in_sizes, int n_in,
                              void* d_out, int out_size, void* d_ws, size_t ws_size,
                              hipStream_t stream) {
  const float* x   = (const float*)d_in[0];
  const int* knn   = (const int*)d_in[1];
  const float* g1  = (const float*)d_in[2];
  const float* b1  = (const float*)d_in[3];
  const float* g2  = (const float*)d_in[4];
  const float* b2  = (const float*)d_in[5];
  const float* Wq  = (const float*)d_in[6];
  const float* Wk  = (const float*)d_in[7];
  const float* Wv  = (const float*)d_in[8];
  const float* Wo  = (const float*)d_in[9];
  const float* W1  = (const float*)d_in[10];
  const float* U1  = (const float*)d_in[11];
  const float* W2  = (const float*)d_in[12];
  const float* W3  = (const float*)d_in[13];
  const float* U3  = (const float*)d_in[14];
  const float* W4  = (const float*)d_in[15];
  const float* U4  = (const float*)d_in[16];
  float* out = (float*)d_out;
  (void)n_in; (void)out_size; (void)ws_size;

  const size_t BN = (size_t)in_sizes[0] / 384;   // 8192

  float* ws    = (float*)d_ws;
  float* xdi   = ws;                          // BN*384 f32 (raw x, de-interleaved [n][c])
  float* xmid  = xdi + BN*384;                // BN*384 f32 (x_mid, de-interleaved)
  _Float16* kmf16 = (_Float16*)(xmid + BN*384);  // BN*384 fp16 [n][128]
  ushort_t* xbp = (ushort_t*)(kmf16 + BN*384);   // BN*384 bf16 (LN1 normalized, de-interleaved)
  ushort_t* qb = xbp + BN*384;                // BN*1152 bf16
  ushort_t* kb = qb + BN*1152;
  ushort_t* vb = kb + BN*1152;
  ushort_t* vT = vb + BN*1152;
  ushort_t* Wall = vT + BN*1152;              // 212992 bf16
  _Float16* Af16 = (_Float16*)(Wall + 212992);   // 65536 fp16
  float* W3t  = (float*)(Af16 + 65536);
  float* U3t  = W3t + 32768;
  float* W4t  = U3t + 32768;
  float* U4t  = W4t + 32768;
  ushort_t* opart = (ushort_t*)(U4t + 32768); // region kept at 4*BN*1152 bf16 (2 splits used; aliasing)
  float* lpart = (float*)(opart + 4*BN*1152); // 2*24*2048 f32
  // YZf/NBf (BN*768 f32 each = 50 MB) alias the opart region: conv1_post runs before attn.
  float* YZf = (float*)opart;
  float* NBf = YZf + BN*768;
  float* nx2 = (float*)qb;   // q dead after x1mid
  float* h3  = (float*)kb;   // k+v dead after attention

  prep_weights<<<1600, 256, 0, stream>>>(Wq, Wk, Wv, Wo, W1, U1, W2, W3, U3, W4, U4,
                                         Wall, Af16, W3t, U3t, W4t, U4t);
  ln1_kernel<<<(int)BN, 128, 0, stream>>>(x, xbp, xdi, g1, b1);
  qkv_conv1_mfma<<<192*4, 256, 0, stream>>>(xbp, Wall, qb, kb, vb, YZf, NBf);
  conv1_post<<<(int)BN, 128, 0, stream>>>(YZf, NBf, knn, kmf16);
  vtrans_kernel<<<(int)(BN*1152/8/256), 256, 0, stream>>>(vb, vT);
  attn_kernel<<<16*24*2, 256, 0, stream>>>(qb, kb, vT, opart, lpart);
  x1mid_mfma<<<256, 384, 0, stream>>>(xdi, opart, lpart, kmf16, Af16, xmid);
  ln2_kernel<<<(int)BN, 128, 0, stream>>>(xmid, nx2, g2, b2);
  conv3_kernel<<<(int)(BN/4), 256, 0, stream>>>(nx2, W3t, U3t, h3);
  conv4_kernel<<<(int)(BN/4), 128, 0, stream>>>(h3, W4t, U4t, xmid, out);
}